// Round 8
// baseline (18.648 us; speedup 1.0000x reference)
//
#include <hip/hip_runtime.h>

// GraphSAGE encoder forward, v8: 4 blocks/CU cohort-staggering probe.
//  v1 25.8 (LDS-GEMM); v2 40.2; v3 33.1; v4 38.2;
//  v5 16.4 (MFMA GEMM, 2 blocks/CU); v6 16.9 (hoist B: neutral);
//  v7 16.3 (16 waves/CU, 2 blocks/CU: flat -> not MLP-limited).
//  Residual theory: phase serialization within each CU's 2 block cohorts
//  (HBM idles ~1.5-2us during sync+GEMM+epilogue). v8: NPB=8, 1024 blocks
//  = 4 cohorts/CU at staggered phases. GEMM on 16-row tile w/ zeroed top
//  half, stores masked to valid 8 rows.
//
// Inputs: emb f32[1M,128], neigh_w f32[8192,10], W f32[256,128], b f32[128],
//         nodes i32[8192], neigh_ids i32[8192,10]. Out f32[8192,128].

#define B_NODES 8192
#define K_NEIGH 10
#define FDIM 128
#define EDIM 128
#define NPB 8
#define THREADS 256

typedef __attribute__((ext_vector_type(8))) short short8v;  // 8 bf16 (4 VGPR)
typedef __attribute__((ext_vector_type(4))) float float4v;  // mfma acc

// XOR-swizzle byte addr (rows are 512B): breaks the stride-512B bank conflict
// on A-frag ds_read_b128. Same map on write and read sides. Maps each 512B
// row-block onto itself (bits 9..11 select the row, bits 4..6 get flipped).
__device__ __forceinline__ int swz(int byte) {
    return byte ^ (((byte >> 9) & 7) << 4);
}

// f32 -> bf16 bits, round-to-nearest-even
__device__ __forceinline__ short f2bf(float f) {
    unsigned u = __builtin_bit_cast(unsigned, f);
    u += 0x7FFFu + ((u >> 16) & 1u);
    return (short)(u >> 16);
}

__global__ __launch_bounds__(THREADS, 4) void sage_fused(
    const float* __restrict__ emb,
    const float* __restrict__ neigh_w,
    const float* __restrict__ Wm,
    const float* __restrict__ bias,
    const int*   __restrict__ nodes,
    const int*   __restrict__ neigh_ids,
    float* __restrict__ out)
{
    __shared__ __align__(16) short x_lds[16 * 2 * FDIM];   // 16-row bf16 tile, 8 KB
    char* xb = (char*)x_lds;

    const int tid = threadIdx.x;
    const int nb0 = blockIdx.x * NPB;
    const int wv  = tid >> 6;           // wave 0..3
    const int l   = tid & 63;

    // zero rows 8..15 (bytes 4096..8191; swz maps this region onto itself):
    // they feed MFMA A-rows whose outputs are masked off at the store.
    *reinterpret_cast<float4*>(xb + 4096 + tid * 16) = make_float4(0.f, 0.f, 0.f, 0.f);

    // ================= Phase 1: gather + aggregate -> bf16 X rows 0..7 ======
    // wave wv handles nodes 2wv, 2wv+1; lane covers 2 dims (float2, 512B/row).
    {
        const int d0 = l * 2;
        const int nlA = wv * 2, nlB = nlA + 1;
        const int gA = nb0 + nlA, gB = nb0 + nlB;

        // metadata for both nodes first (independent, in flight together)
        const int2*   ipA = reinterpret_cast<const int2*>(neigh_ids + (size_t)gA * K_NEIGH);
        const int2*   ipB = reinterpret_cast<const int2*>(neigh_ids + (size_t)gB * K_NEIGH);
        const float2* wpA = reinterpret_cast<const float2*>(neigh_w  + (size_t)gA * K_NEIGH);
        const float2* wpB = reinterpret_cast<const float2*>(neigh_w  + (size_t)gB * K_NEIGH);
        int2 idA[5], idB[5];
        float2 wA[5], wB[5];
#pragma unroll
        for (int k = 0; k < 5; ++k) idA[k] = ipA[k];
#pragma unroll
        for (int k = 0; k < 5; ++k) idB[k] = ipB[k];
#pragma unroll
        for (int k = 0; k < 5; ++k) wA[k] = wpA[k];
#pragma unroll
        for (int k = 0; k < 5; ++k) wB[k] = wpB[k];
        const int sidA = nodes[gA];
        const int sidB = nodes[gB];

        float wsA = 0.f, wsB = 0.f;
#pragma unroll
        for (int k = 0; k < 5; ++k) { wsA += wA[k].x + wA[k].y; wsB += wB[k].x + wB[k].y; }
        const float invA = 1.f / wsA, invB = 1.f / wsB;

        const float2 svA = *reinterpret_cast<const float2*>(&emb[(size_t)sidA * FDIM + d0]);
        const float2 svB = *reinterpret_cast<const float2*>(&emb[(size_t)sidB * FDIM + d0]);

        float axA = 0.f, ayA = 0.f, axB = 0.f, ayB = 0.f;
#pragma unroll
        for (int k = 0; k < 5; ++k) {
            const float2 vxA = *reinterpret_cast<const float2*>(&emb[(size_t)idA[k].x * FDIM + d0]);
            const float2 vyA = *reinterpret_cast<const float2*>(&emb[(size_t)idA[k].y * FDIM + d0]);
            const float2 vxB = *reinterpret_cast<const float2*>(&emb[(size_t)idB[k].x * FDIM + d0]);
            const float2 vyB = *reinterpret_cast<const float2*>(&emb[(size_t)idB[k].y * FDIM + d0]);
            axA = fmaf(wA[k].x, vxA.x, axA); ayA = fmaf(wA[k].x, vxA.y, ayA);
            axA = fmaf(wA[k].y, vyA.x, axA); ayA = fmaf(wA[k].y, vyA.y, ayA);
            axB = fmaf(wB[k].x, vxB.x, axB); ayB = fmaf(wB[k].x, vxB.y, ayB);
            axB = fmaf(wB[k].y, vyB.x, axB); ayB = fmaf(wB[k].y, vyB.y, ayB);
        }

        ushort2 t;
        t.x = (unsigned short)f2bf(svA.x); t.y = (unsigned short)f2bf(svA.y);
        *reinterpret_cast<ushort2*>(xb + swz(nlA * 512 + l * 4)) = t;
        t.x = (unsigned short)f2bf(axA * invA); t.y = (unsigned short)f2bf(ayA * invA);
        *reinterpret_cast<ushort2*>(xb + swz(nlA * 512 + 256 + l * 4)) = t;
        t.x = (unsigned short)f2bf(svB.x); t.y = (unsigned short)f2bf(svB.y);
        *reinterpret_cast<ushort2*>(xb + swz(nlB * 512 + l * 4)) = t;
        t.x = (unsigned short)f2bf(axB * invB); t.y = (unsigned short)f2bf(ayB * invB);
        *reinterpret_cast<ushort2*>(xb + swz(nlB * 512 + 256 + l * 4)) = t;
    }
    __syncthreads();

    // ================= Phase 2: X[16,256] @ W[256,128] via MFMA =============
    // wave wv owns cols [wv*32, wv*32+32): two 16x16 N-tiles, 16 MFMAs.
    // A rows 8..15 are zeros; D rows >= 8 are masked at the store.
    {
        const int lg = l >> 4;           // k-group / row-group (0..3)
        const int li = l & 15;
        const int e0 = wv * 32;

        float4v acc0 = {0.f, 0.f, 0.f, 0.f};
        float4v acc1 = {0.f, 0.f, 0.f, 0.f};

#pragma unroll
        for (int kblk = 0; kblk < 8; ++kblk) {
            const short8v a = *reinterpret_cast<const short8v*>(
                xb + swz(li * 512 + kblk * 64 + lg * 16));

            const int kb = kblk * 32 + lg * 8;
            short8v b0, b1;
#pragma unroll
            for (int j = 0; j < 8; ++j) {
                b0[j] = f2bf(Wm[(size_t)(kb + j) * EDIM + e0 + li]);
                b1[j] = f2bf(Wm[(size_t)(kb + j) * EDIM + e0 + 16 + li]);
            }
            acc0 = __builtin_amdgcn_mfma_f32_16x16x32_bf16(a, b0, acc0, 0, 0, 0);
            acc1 = __builtin_amdgcn_mfma_f32_16x16x32_bf16(a, b1, acc1, 0, 0, 0);
        }

        // epilogue: rows (l>>4)*4 + r; only rows 0..7 are valid (lg < 2)
        if (lg < 2) {
            const float bv0 = bias[e0 + li];
            const float bv1 = bias[e0 + 16 + li];
#pragma unroll
            for (int r = 0; r < 4; ++r) {
                const int row = nb0 + lg * 4 + r;
                const float v0 = acc0[r] + bv0;
                const float v1 = acc1[r] + bv1;
                out[(size_t)row * EDIM + e0 + li]      = v0 / (1.f + __expf(-v0));
                out[(size_t)row * EDIM + e0 + 16 + li] = v1 / (1.f + __expf(-v1));
            }
        }
    }
}

extern "C" void kernel_launch(void* const* d_in, const int* in_sizes, int n_in,
                              void* d_out, int out_size, void* d_ws, size_t ws_size,
                              hipStream_t stream) {
    const float* emb       = (const float*)d_in[0];
    const float* neigh_w   = (const float*)d_in[1];
    const float* Wm        = (const float*)d_in[2];
    const float* bias      = (const float*)d_in[3];
    const int*   nodes     = (const int*)d_in[4];
    const int*   neigh_ids = (const int*)d_in[5];
    float* out = (float*)d_out;

    sage_fused<<<dim3(B_NODES / NPB), dim3(THREADS), 0, stream>>>(
        emb, neigh_w, Wm, bias, nodes, neigh_ids, out);
}

// Round 9
// 17.111 us; speedup vs baseline: 1.0898x; 1.0898x over previous
//
#include <hip/hip_runtime.h>

// GraphSAGE encoder forward, v9: v7 + non-temporal emb loads / out stores.
//  v1 25.8; v2 40.2; v3 33.1; v4 38.2; v5 16.4; v6 16.9 (hoist-B neutral);
//  v7 16.26 (best: 8-wave blocks, MFMA GEMM); v8 18.6 (W-traffic doubled).
//  Gather is pinned at ~15us (~3.2 TB/s eff) across 5 variants. Last lever:
//  the 46MB single-use sweep thrashes L2 (4MB/XCD), evicting W/bias/meta.
//  v9 marks emb reads + out writes non-temporal so L2 keeps the reused data.
//
// Inputs: emb f32[1M,128], neigh_w f32[8192,10], W f32[256,128], b f32[128],
//         nodes i32[8192], neigh_ids i32[8192,10]. Out f32[8192,128].

#define B_NODES 8192
#define K_NEIGH 10
#define FDIM 128
#define EDIM 128
#define NPB 16
#define THREADS 512

typedef __attribute__((ext_vector_type(8))) short short8v;  // 8 bf16 (4 VGPR)
typedef __attribute__((ext_vector_type(4))) float float4v;  // mfma acc
typedef __attribute__((ext_vector_type(2))) float f32x2;

// XOR-swizzle byte addr (rows are 512B): breaks the stride-512B bank conflict
// on A-frag ds_read_b128. Same map on write and read sides.
__device__ __forceinline__ int swz(int byte) {
    return byte ^ (((byte >> 9) & 7) << 4);
}

// f32 -> bf16 bits, round-to-nearest-even
__device__ __forceinline__ short f2bf(float f) {
    unsigned u = __builtin_bit_cast(unsigned, f);
    u += 0x7FFFu + ((u >> 16) & 1u);
    return (short)(u >> 16);
}

// non-temporal 8B load (single-use gather rows: don't allocate in L2)
__device__ __forceinline__ f32x2 ntload2(const float* p) {
    return __builtin_nontemporal_load(reinterpret_cast<const f32x2*>(p));
}

__global__ __launch_bounds__(THREADS, 4) void sage_fused(
    const float* __restrict__ emb,
    const float* __restrict__ neigh_w,
    const float* __restrict__ Wm,
    const float* __restrict__ bias,
    const int*   __restrict__ nodes,
    const int*   __restrict__ neigh_ids,
    float* __restrict__ out)
{
    __shared__ __align__(16) short x_lds[NPB * 2 * FDIM];   // bf16 X tile, 8 KB
    char* xb = (char*)x_lds;

    const int tid  = threadIdx.x;
    const int nb0  = blockIdx.x * NPB;
    const int wv   = tid >> 6;          // wave 0..7
    const int l    = tid & 63;

    // ================= Phase 1: gather + aggregate -> bf16 X tile ===========
    // wave wv handles nodes 2wv, 2wv+1; lane covers 2 dims (float2, 512B/row).
    {
        const int d0 = l * 2;
#pragma unroll
        for (int nn = 0; nn < 2; ++nn) {
            const int nl = wv * 2 + nn;
            const int g  = nb0 + nl;

            // metadata: vectorized uniform loads (reused-class data, normal)
            const int2*   ip = reinterpret_cast<const int2*>(neigh_ids + (size_t)g * K_NEIGH);
            const float2* wp = reinterpret_cast<const float2*>(neigh_w  + (size_t)g * K_NEIGH);
            int2   id2[5];
            float2 w2[5];
#pragma unroll
            for (int k = 0; k < 5; ++k) id2[k] = ip[k];
#pragma unroll
            for (int k = 0; k < 5; ++k) w2[k]  = wp[k];
            const int sid = nodes[g];

            float wsum = 0.f;
#pragma unroll
            for (int k = 0; k < 5; ++k) wsum += w2[k].x + w2[k].y;
            const float inv = 1.f / wsum;

            const f32x2 sv = ntload2(&emb[(size_t)sid * FDIM + d0]);

            float ax = 0.f, ay = 0.f;
#pragma unroll
            for (int k = 0; k < 5; ++k) {
                const f32x2 vx = ntload2(&emb[(size_t)id2[k].x * FDIM + d0]);
                const f32x2 vy = ntload2(&emb[(size_t)id2[k].y * FDIM + d0]);
                ax = fmaf(w2[k].x, vx.x, ax); ay = fmaf(w2[k].x, vx.y, ay);
                ax = fmaf(w2[k].y, vy.x, ax); ay = fmaf(w2[k].y, vy.y, ay);
            }

            ushort2 s2, g2;
            s2.x = (unsigned short)f2bf(sv.x);      s2.y = (unsigned short)f2bf(sv.y);
            g2.x = (unsigned short)f2bf(ax * inv);  g2.y = (unsigned short)f2bf(ay * inv);
            *reinterpret_cast<ushort2*>(xb + swz(nl * 512 + l * 4))       = s2;
            *reinterpret_cast<ushort2*>(xb + swz(nl * 512 + 256 + l * 4)) = g2;
        }
    }
    __syncthreads();

    // ================= Phase 2: X[16,256] @ W[256,128] via MFMA =============
    // wave wv owns output cols [wv*16, wv*16+16): ONE 16x16 N-tile, 8 MFMAs.
    // A-frag: lane l -> X[row=l&15][k=(l>>4)*8+j] (one swizzled b128 read)
    // B-frag: lane l -> W[k=(l>>4)*8+j][wv*16 + (l&15)] (8 coalesced f32 loads)
    // D:      lane l reg r -> out[row=(l>>4)*4+r][wv*16 + (l&15)]
    {
        const int lg = l >> 4;           // k-group / row-group (0..3)
        const int li = l & 15;
        const int ec = wv * 16 + li;     // output column

        float4v acc = {0.f, 0.f, 0.f, 0.f};
#pragma unroll
        for (int kblk = 0; kblk < 8; ++kblk) {
            const short8v a = *reinterpret_cast<const short8v*>(
                xb + swz(li * 512 + kblk * 64 + lg * 16));

            const int kb = kblk * 32 + lg * 8;
            short8v b;
#pragma unroll
            for (int j = 0; j < 8; ++j)
                b[j] = f2bf(Wm[(size_t)(kb + j) * EDIM + ec]);

            acc = __builtin_amdgcn_mfma_f32_16x16x32_bf16(a, b, acc, 0, 0, 0);
        }

        const float bv = bias[ec];
#pragma unroll
        for (int r = 0; r < 4; ++r) {
            const int row = nb0 + lg * 4 + r;
            const float v = acc[r] + bv;
            // single-use output: non-temporal store, keep L2 for W/meta
            __builtin_nontemporal_store(v / (1.f + __expf(-v)),
                                        &out[(size_t)row * EDIM + ec]);
        }
    }
}

extern "C" void kernel_launch(void* const* d_in, const int* in_sizes, int n_in,
                              void* d_out, int out_size, void* d_ws, size_t ws_size,
                              hipStream_t stream) {
    const float* emb       = (const float*)d_in[0];
    const float* neigh_w   = (const float*)d_in[1];
    const float* Wm        = (const float*)d_in[2];
    const float* bias      = (const float*)d_in[3];
    const int*   nodes     = (const int*)d_in[4];
    const int*   neigh_ids = (const int*)d_in[5];
    float* out = (float*)d_out;

    sage_fused<<<dim3(B_NODES / NPB), dim3(THREADS), 0, stream>>>(
        emb, neigh_w, Wm, bias, nodes, neigh_ids, out);
}

// Round 10
// 16.149 us; speedup vs baseline: 1.1548x; 1.0596x over previous
//
#include <hip/hip_runtime.h>

// GraphSAGE encoder forward, v10 (FINAL candidate): v7 + nt stores only.
//  Journal: v1 25.8 (LDS-GEMM); v2 40.2 (W dup); v3 33.1 (overpipelined);
//  v4 38.2 (split); v5 16.4 (MFMA GEMM); v6 16.9 (hoist-B neutral);
//  v7 16.26 (BEST: 8-wave blocks, float2 gather, per-wave 16-col MFMA tile);
//  v8 18.6 (NPB=8 doubled W traffic); v9 17.1 (nt loads forfeit L2 hits).
//  Roofline: 46MB random 512B-row gather is DRAM page-activate-limited at
//  ~3.1 TB/s (invariant across 6 structural variants; streaming fills hit
//  6.7-7 TB/s on the same chip). v10 keeps normal loads, nt store on out.
//
// Inputs: emb f32[1M,128], neigh_w f32[8192,10], W f32[256,128], b f32[128],
//         nodes i32[8192], neigh_ids i32[8192,10]. Out f32[8192,128].

#define B_NODES 8192
#define K_NEIGH 10
#define FDIM 128
#define EDIM 128
#define NPB 16
#define THREADS 512

typedef __attribute__((ext_vector_type(8))) short short8v;  // 8 bf16 (4 VGPR)
typedef __attribute__((ext_vector_type(4))) float float4v;  // mfma acc

// XOR-swizzle byte addr (rows are 512B): breaks the stride-512B bank conflict
// on A-frag ds_read_b128. Same map on write and read sides.
__device__ __forceinline__ int swz(int byte) {
    return byte ^ (((byte >> 9) & 7) << 4);
}

// f32 -> bf16 bits, round-to-nearest-even
__device__ __forceinline__ short f2bf(float f) {
    unsigned u = __builtin_bit_cast(unsigned, f);
    u += 0x7FFFu + ((u >> 16) & 1u);
    return (short)(u >> 16);
}

__global__ __launch_bounds__(THREADS, 4) void sage_fused(
    const float* __restrict__ emb,
    const float* __restrict__ neigh_w,
    const float* __restrict__ Wm,
    const float* __restrict__ bias,
    const int*   __restrict__ nodes,
    const int*   __restrict__ neigh_ids,
    float* __restrict__ out)
{
    __shared__ __align__(16) short x_lds[NPB * 2 * FDIM];   // bf16 X tile, 8 KB
    char* xb = (char*)x_lds;

    const int tid  = threadIdx.x;
    const int nb0  = blockIdx.x * NPB;
    const int wv   = tid >> 6;          // wave 0..7
    const int l    = tid & 63;

    // ================= Phase 1: gather + aggregate -> bf16 X tile ===========
    // wave wv handles nodes 2wv, 2wv+1; lane covers 2 dims (float2, 512B/row).
    {
        const int d0 = l * 2;
#pragma unroll
        for (int nn = 0; nn < 2; ++nn) {
            const int nl = wv * 2 + nn;
            const int g  = nb0 + nl;

            // metadata: vectorized uniform loads (40B each, 8B-aligned)
            const int2*   ip = reinterpret_cast<const int2*>(neigh_ids + (size_t)g * K_NEIGH);
            const float2* wp = reinterpret_cast<const float2*>(neigh_w  + (size_t)g * K_NEIGH);
            int2   id2[5];
            float2 w2[5];
#pragma unroll
            for (int k = 0; k < 5; ++k) id2[k] = ip[k];
#pragma unroll
            for (int k = 0; k < 5; ++k) w2[k]  = wp[k];
            const int sid = nodes[g];

            float wsum = 0.f;
#pragma unroll
            for (int k = 0; k < 5; ++k) wsum += w2[k].x + w2[k].y;
            const float inv = 1.f / wsum;

            const float2 sv = *reinterpret_cast<const float2*>(&emb[(size_t)sid * FDIM + d0]);

            float ax = 0.f, ay = 0.f;
#pragma unroll
            for (int k = 0; k < 5; ++k) {
                const float2 vx = *reinterpret_cast<const float2*>(&emb[(size_t)id2[k].x * FDIM + d0]);
                const float2 vy = *reinterpret_cast<const float2*>(&emb[(size_t)id2[k].y * FDIM + d0]);
                ax = fmaf(w2[k].x, vx.x, ax); ay = fmaf(w2[k].x, vx.y, ay);
                ax = fmaf(w2[k].y, vy.x, ax); ay = fmaf(w2[k].y, vy.y, ay);
            }

            ushort2 s2, g2;
            s2.x = (unsigned short)f2bf(sv.x);      s2.y = (unsigned short)f2bf(sv.y);
            g2.x = (unsigned short)f2bf(ax * inv);  g2.y = (unsigned short)f2bf(ay * inv);
            *reinterpret_cast<ushort2*>(xb + swz(nl * 512 + l * 4))       = s2;
            *reinterpret_cast<ushort2*>(xb + swz(nl * 512 + 256 + l * 4)) = g2;
        }
    }
    __syncthreads();

    // ================= Phase 2: X[16,256] @ W[256,128] via MFMA =============
    // wave wv owns output cols [wv*16, wv*16+16): ONE 16x16 N-tile, 8 MFMAs.
    // A-frag: lane l -> X[row=l&15][k=(l>>4)*8+j] (one swizzled b128 read)
    // B-frag: lane l -> W[k=(l>>4)*8+j][wv*16 + (l&15)] (8 coalesced f32 loads)
    // D:      lane l reg r -> out[row=(l>>4)*4+r][wv*16 + (l&15)]
    {
        const int lg = l >> 4;           // k-group / row-group (0..3)
        const int li = l & 15;
        const int ec = wv * 16 + li;     // output column

        float4v acc = {0.f, 0.f, 0.f, 0.f};
#pragma unroll
        for (int kblk = 0; kblk < 8; ++kblk) {
            const short8v a = *reinterpret_cast<const short8v*>(
                xb + swz(li * 512 + kblk * 64 + lg * 16));

            const int kb = kblk * 32 + lg * 8;
            short8v b;
#pragma unroll
            for (int j = 0; j < 8; ++j)
                b[j] = f2bf(Wm[(size_t)(kb + j) * EDIM + ec]);

            acc = __builtin_amdgcn_mfma_f32_16x16x32_bf16(a, b, acc, 0, 0, 0);
        }

        const float bv = bias[ec];
#pragma unroll
        for (int r = 0; r < 4; ++r) {
            const int row = nb0 + lg * 4 + r;
            const float v = acc[r] + bv;
            // write-once output: nt store skips L2 write-allocate
            __builtin_nontemporal_store(v / (1.f + __expf(-v)),
                                        &out[(size_t)row * EDIM + ec]);
        }
    }
}

extern "C" void kernel_launch(void* const* d_in, const int* in_sizes, int n_in,
                              void* d_out, int out_size, void* d_ws, size_t ws_size,
                              hipStream_t stream) {
    const float* emb       = (const float*)d_in[0];
    const float* neigh_w   = (const float*)d_in[1];
    const float* Wm        = (const float*)d_in[2];
    const float* bias      = (const float*)d_in[3];
    const int*   nodes     = (const int*)d_in[4];
    const int*   neigh_ids = (const int*)d_in[5];
    float* out = (float*)d_out;

    sage_fused<<<dim3(B_NODES / NPB), dim3(THREADS), 0, stream>>>(
        emb, neigh_w, Wm, bias, nodes, neigh_ids, out);
}